// Round 3
// baseline (1530.147 us; speedup 1.0000x reference)
//
#include <hip/hip_runtime.h>
#include <hip/hip_bf16.h>
#include <math.h>

#define BB 8
#define LL 2048
#define DD 128
#define GG 16   // state-row groups (8 rows per group, one wave each)

// ---------------------------------------------------------------------------
// Generic C[M,O] = X[M,128] @ W[O,128]^T, optional sigmoid epilogue.
// grid (M/32, O/64), block 256. LDS-tiled, fp32 vector FMA.
// ---------------------------------------------------------------------------
__global__ __launch_bounds__(256) void gemm_kernel(
    const float* __restrict__ X, int ldx,
    const float* __restrict__ W,
    float* __restrict__ C, int ldc,
    int applySig)
{
    __shared__ float Xs[32 * 132];
    __shared__ float Ws[64 * 132];
    const int tid = threadIdx.x;
    const int m0 = blockIdx.x * 32;
    const int o0 = blockIdx.y * 64;
    {
        int row = tid >> 3, cg = tid & 7;
        const float* src = X + (size_t)(m0 + row) * ldx + cg * 16;
        float* dst = Xs + row * 132 + cg * 16;
#pragma unroll
        for (int u = 0; u < 4; ++u)
            *(float4*)(dst + 4 * u) = *(const float4*)(src + 4 * u);
    }
    {
        int o = tid >> 2, cg = tid & 3;
        const float* src = W + (size_t)(o0 + o) * 128 + cg * 32;
        float* dst = Ws + o * 132 + cg * 32;
#pragma unroll
        for (int u = 0; u < 8; ++u)
            *(float4*)(dst + 4 * u) = *(const float4*)(src + 4 * u);
    }
    __syncthreads();
    const int tx = tid & 31, ty = tid >> 5;
    float acc[4][2] = {};
    const float* xb = Xs + (ty * 4) * 132;
    const float* wb = Ws + (tx * 2) * 132;
    for (int k0 = 0; k0 < 128; k0 += 4) {
        float4 xr[4], wr[2];
#pragma unroll
        for (int r = 0; r < 4; ++r) xr[r] = *(const float4*)(xb + r * 132 + k0);
#pragma unroll
        for (int cc = 0; cc < 2; ++cc) wr[cc] = *(const float4*)(wb + cc * 132 + k0);
#pragma unroll
        for (int r = 0; r < 4; ++r)
#pragma unroll
            for (int cc = 0; cc < 2; ++cc) {
                acc[r][cc] += xr[r].x * wr[cc].x + xr[r].y * wr[cc].y
                            + xr[r].z * wr[cc].z + xr[r].w * wr[cc].w;
            }
    }
#pragma unroll
    for (int r = 0; r < 4; ++r)
#pragma unroll
        for (int cc = 0; cc < 2; ++cc) {
            float v = acc[r][cc];
            if (applySig) v = 1.0f / (1.0f + __expf(-v));
            C[(size_t)(m0 + ty * 4 + r) * ldc + o0 + tx * 2 + cc] = v;
        }
}

// ---------------------------------------------------------------------------
// Depthwise conv(K=3, pad 1) + sigmoid + L2-normalize over D for q and k.
// Emits qn [M,128] and kam [M,256] = [ k_norm | m=beta*k_norm ].
// One wave per (b,l); lane handles dims d0 = 2*lane, 2*lane+1.
// ---------------------------------------------------------------------------
__global__ __launch_bounds__(256) void convnorm_kernel(
    const float* __restrict__ qkv,
    const float* __restrict__ qw, const float* __restrict__ qb,
    const float* __restrict__ kw, const float* __restrict__ kb,
    const float* __restrict__ ab,
    float* __restrict__ qn, float* __restrict__ kam)
{
    const int tid = threadIdx.x;
    const int lane = tid & 63;
    const int wid = tid >> 6;
    const int m = blockIdx.x * 4 + wid;     // b*L + l
    const int l = m & (LL - 1);
    const int d0 = lane * 2;
    float yq0 = qb[d0], yq1 = qb[d0 + 1];
    float yk0 = kb[d0], yk1 = kb[d0 + 1];
#pragma unroll
    for (int tau = 0; tau < 3; ++tau) {
        int lp = l + tau - 1;
        if (lp >= 0 && lp < LL) {
            const float* base = qkv + (size_t)(m + tau - 1) * 512;
            yq0 += base[d0]       * qw[d0 * 3 + tau];
            yq1 += base[d0 + 1]   * qw[(d0 + 1) * 3 + tau];
            yk0 += base[128 + d0]     * kw[d0 * 3 + tau];
            yk1 += base[128 + d0 + 1] * kw[(d0 + 1) * 3 + tau];
        }
    }
    yq0 = 1.0f / (1.0f + __expf(-yq0));
    yq1 = 1.0f / (1.0f + __expf(-yq1));
    yk0 = 1.0f / (1.0f + __expf(-yk0));
    yk1 = 1.0f / (1.0f + __expf(-yk1));
    float sq = yq0 * yq0 + yq1 * yq1;
    float sk = yk0 * yk0 + yk1 * yk1;
#pragma unroll
    for (int msk = 1; msk <= 32; msk <<= 1) {
        sq += __shfl_xor(sq, msk);
        sk += __shfl_xor(sk, msk);
    }
    float rq = 1.0f / fmaxf(sqrtf(sq), 1e-12f);
    float rk = 1.0f / fmaxf(sqrtf(sk), 1e-12f);
    float k0n = yk0 * rk, k1n = yk1 * rk;
    size_t oq = (size_t)m * DD + d0;
    qn[oq] = yq0 * rq; qn[oq + 1] = yq1 * rq;
    float b0 = ab[(size_t)m * 256 + 128 + d0];
    float b1 = ab[(size_t)m * 256 + 128 + d0 + 1];
    size_t ok = (size_t)m * 256 + d0;
    kam[ok] = k0n;            kam[ok + 1] = k1n;
    kam[ok + 128] = b0 * k0n; kam[ok + 129] = b1 * k1n;
}

// ---------------------------------------------------------------------------
// Barrier-free sequential delta-rule recurrence, explicit depth-2 pipeline.
// Grid 128 = B*GG workgroups of 64 threads (ONE wave each).
// Wave (b,g) owns state rows rbase=g*8..+8 of batch b in registers, twice:
//   A: lane (iA=lane>>3, c=lane&7) holds S[iA][c*16..+16)  -> SA[16]
//   B: lane holds cols {lane, lane+64} of all 8 rows       -> SB[8][2]
// Main loop manually unrolled x2 with statically-indexed double buffers so
// the compiler CANNOT collapse the prefetch (R2 lesson: VGPR=72 proved it
// merged the buffers and exposed full load latency every step).
// ---------------------------------------------------------------------------
__global__ __launch_bounds__(64) void recur_kernel(
    const float* __restrict__ qn, const float* __restrict__ kam,
    const float* __restrict__ ab, const float* __restrict__ qkv,
    const float* __restrict__ state,
    __hip_bfloat16* __restrict__ pout, float* __restrict__ sfin)
{
    const int lane = threadIdx.x;
    const int b = blockIdx.x >> 4;
    const int g = blockIdx.x & (GG - 1);
    const int rbase = g * 8;
    const int iA = lane >> 3;
    const int c = lane & 7;
    const int colA = c * 16;
    const size_t mb = (size_t)b * LL;

    float SA[16];
    {
        const float* sp = state + ((size_t)b * DD + rbase + iA) * DD + colA;
#pragma unroll
        for (int u = 0; u < 4; ++u) {
            float4 t4 = *(const float4*)(sp + 4 * u);
            SA[4 * u + 0] = t4.x; SA[4 * u + 1] = t4.y;
            SA[4 * u + 2] = t4.z; SA[4 * u + 3] = t4.w;
        }
    }
    float SB[8][2];
#pragma unroll
    for (int r = 0; r < 8; ++r) {
        const float* sp = state + ((size_t)b * DD + rbase + r) * DD + lane;
        SB[r][0] = sp[0]; SB[r][1] = sp[64];
    }

    // streaming pointers (advance once per PREFETCH)
    const float* pA  = kam + mb * 256 + colA;   // k at +0, m at +128 floats
    const float* pAa = ab  + mb * 256 + colA;   // alpha (first half of ab)
    const float* pBk = kam + mb * 256 + lane;   // mB0 at +128, mB1 at +192
    const float* pBa = ab  + mb * 256 + lane;   // aB0 at +0,  aB1 at +64
    const float* pV  = qkv + mb * 512 + 256 + rbase;
    const float* pQ  = qn  + mb * DD + rbase;
    __hip_bfloat16* po = pout + ((size_t)g * (BB * LL) + mb) * DD + lane;

    // double-buffered per-step registers (statically indexed!)
    float ka[2][16], aa[2][16], ma[2][16];
    float vv[2][8], qv[2][8];
    float vA[2], aB0[2], aB1[2], mB0[2], mB1[2];

#define PREFETCH(B)                                                          \
    do {                                                                     \
        _Pragma("unroll")                                                    \
        for (int u = 0; u < 4; ++u) {                                        \
            float4 t4;                                                       \
            t4 = *(const float4*)(pA + 4 * u);                               \
            ka[B][4*u] = t4.x; ka[B][4*u+1] = t4.y;                          \
            ka[B][4*u+2] = t4.z; ka[B][4*u+3] = t4.w;                        \
            t4 = *(const float4*)(pA + 128 + 4 * u);                         \
            ma[B][4*u] = t4.x; ma[B][4*u+1] = t4.y;                          \
            ma[B][4*u+2] = t4.z; ma[B][4*u+3] = t4.w;                        \
            t4 = *(const float4*)(pAa + 4 * u);                              \
            aa[B][4*u] = t4.x; aa[B][4*u+1] = t4.y;                          \
            aa[B][4*u+2] = t4.z; aa[B][4*u+3] = t4.w;                        \
        }                                                                    \
        {                                                                    \
            float4 t4;                                                       \
            t4 = *(const float4*)pV;                                         \
            vv[B][0] = t4.x; vv[B][1] = t4.y; vv[B][2] = t4.z; vv[B][3] = t4.w; \
            t4 = *(const float4*)(pV + 4);                                   \
            vv[B][4] = t4.x; vv[B][5] = t4.y; vv[B][6] = t4.z; vv[B][7] = t4.w; \
            t4 = *(const float4*)pQ;                                         \
            qv[B][0] = t4.x; qv[B][1] = t4.y; qv[B][2] = t4.z; qv[B][3] = t4.w; \
            t4 = *(const float4*)(pQ + 4);                                   \
            qv[B][4] = t4.x; qv[B][5] = t4.y; qv[B][6] = t4.z; qv[B][7] = t4.w; \
        }                                                                    \
        vA[B] = pV[iA];                                                      \
        aB0[B] = pBa[0];   aB1[B] = pBa[64];                                 \
        mB0[B] = pBk[128]; mB1[B] = pBk[192];                                \
        pA += 256; pAa += 256; pBk += 256; pBa += 256; pV += 512; pQ += DD;  \
    } while (0)

#define STEP(B)                                                              \
    do {                                                                     \
        float p = SA[0] * ka[B][0];                                          \
        _Pragma("unroll")                                                    \
        for (int u = 1; u < 16; ++u) p = fmaf(SA[u], ka[B][u], p);           \
        p += __shfl_xor(p, 1);                                               \
        p += __shfl_xor(p, 2);                                               \
        p += __shfl_xor(p, 4);                                               \
        float sk[8];                                                         \
        _Pragma("unroll")                                                    \
        for (int r = 0; r < 8; ++r) sk[r] = __shfl(p, r * 8 + c);            \
        _Pragma("unroll")                                                    \
        for (int u = 0; u < 16; ++u) {                                       \
            float w = fmaf(-aa[B][u], p, vA[B]);                             \
            SA[u] = fmaf(ma[B][u], w, aa[B][u] * SA[u]);                     \
        }                                                                    \
        float po0 = 0.0f, po1 = 0.0f;                                        \
        _Pragma("unroll")                                                    \
        for (int r = 0; r < 8; ++r) {                                        \
            float w0 = fmaf(-aB0[B], sk[r], vv[B][r]);                       \
            SB[r][0] = fmaf(mB0[B], w0, aB0[B] * SB[r][0]);                  \
            po0 = fmaf(qv[B][r], SB[r][0], po0);                             \
            float w1 = fmaf(-aB1[B], sk[r], vv[B][r]);                       \
            SB[r][1] = fmaf(mB1[B], w1, aB1[B] * SB[r][1]);                  \
            po1 = fmaf(qv[B][r], SB[r][1], po1);                             \
        }                                                                    \
        po[0]  = __float2bfloat16(po0);                                      \
        po[64] = __float2bfloat16(po1);                                      \
        po += DD;                                                            \
    } while (0)

    PREFETCH(0);    // t = 0
    PREFETCH(1);    // t = 1
    for (int t = 0; t < LL; t += 2) {
        STEP(0);
        PREFETCH(0);    // t+2 (tail overruns into adjacent ws buffers: safe)
        STEP(1);
        PREFETCH(1);    // t+3
    }
#undef PREFETCH
#undef STEP

    {
        float* sp = sfin + ((size_t)b * DD + rbase + iA) * DD + colA;
#pragma unroll
        for (int u = 0; u < 4; ++u) {
            float4 o4 = {SA[4*u], SA[4*u+1], SA[4*u+2], SA[4*u+3]};
            *(float4*)(sp + 4 * u) = o4;
        }
    }
}

// ---------------------------------------------------------------------------
// out_core = silu(sum_g pout[g])   (pout bf16 -> fp32 accumulate)
// ---------------------------------------------------------------------------
__global__ __launch_bounds__(256) void combine_silu_kernel(
    const ushort* __restrict__ pout, float* __restrict__ oc)
{
    const size_t N = (size_t)BB * LL * DD;
    size_t idx = ((size_t)blockIdx.x * 256 + threadIdx.x) * 4;
    float s0 = 0, s1 = 0, s2 = 0, s3 = 0;
#pragma unroll
    for (int g = 0; g < GG; ++g) {
        uint2 u = *(const uint2*)(pout + g * N + idx);
        s0 += __uint_as_float((u.x & 0xffffu) << 16);
        s1 += __uint_as_float(u.x & 0xffff0000u);
        s2 += __uint_as_float((u.y & 0xffffu) << 16);
        s3 += __uint_as_float(u.y & 0xffff0000u);
    }
    float4 r;
    r.x = s0 / (1.0f + __expf(-s0));
    r.y = s1 / (1.0f + __expf(-s1));
    r.z = s2 / (1.0f + __expf(-s2));
    r.w = s3 / (1.0f + __expf(-s3));
    *(float4*)(oc + idx) = r;
}

// ---------------------------------------------------------------------------
// d_out = y * rsqrt(mean(y^2)+1e-6) * rms_w + residual. One wave per (b,l).
// ---------------------------------------------------------------------------
__global__ __launch_bounds__(256) void rms_res_kernel(
    const float* __restrict__ y, const float* __restrict__ res,
    const float* __restrict__ rmsw, float* __restrict__ out)
{
    const int tid = threadIdx.x;
    const int lane = tid & 63;
    const int wid = tid >> 6;
    const int m = blockIdx.x * 4 + wid;
    const int d0 = lane * 2;
    size_t o = (size_t)m * DD + d0;
    float2 yv = *(const float2*)(y + o);
    float ss = yv.x * yv.x + yv.y * yv.y;
#pragma unroll
    for (int msk = 1; msk <= 32; msk <<= 1) ss += __shfl_xor(ss, msk);
    float r = rsqrtf(ss * (1.0f / 128.0f) + 1e-6f);
    float2 rv = *(const float2*)(res + o);
    out[o]     = yv.x * r * rmsw[d0]     + rv.x;
    out[o + 1] = yv.y * r * rmsw[d0 + 1] + rv.y;
}

// ---------------------------------------------------------------------------
extern "C" void kernel_launch(void* const* d_in, const int* in_sizes, int n_in,
                              void* d_out, int out_size, void* d_ws, size_t ws_size,
                              hipStream_t stream)
{
    const float* x      = (const float*)d_in[0];
    const float* state  = (const float*)d_in[1];
    const float* W_in   = (const float*)d_in[2];
    const float* W_gate = (const float*)d_in[3];
    const float* W_out  = (const float*)d_in[4];
    const float* W_res  = (const float*)d_in[5];
    const float* qcw    = (const float*)d_in[6];
    const float* qcb    = (const float*)d_in[7];
    const float* kcw    = (const float*)d_in[8];
    const float* kcb    = (const float*)d_in[9];
    const float* rmsw   = (const float*)d_in[10];
    float* out  = (float*)d_out;
    float* sfin = out + (size_t)BB * LL * DD;

    const size_t M = (size_t)BB * LL;            // 16384
    float* ws = (float*)d_ws;
    float* qkv = ws;                 ws += M * 512;           // 33.5 MB
    float* abv = ws;                 ws += M * 256;           // 16.8 MB
    float* res = ws;                 ws += M * DD;            //  8.4 MB
    float* qnb = ws;                 ws += M * DD;            //  8.4 MB
    float* kam = ws;                 ws += M * 256;           // 16.8 MB
    __hip_bfloat16* po = (__hip_bfloat16*)ws;                 // 67 MB (GG slices)
    // reuse (sequential stream order makes this safe):
    float* oc = qnb;   // combine output: recurrence no longer reads qnb after
    float* yb = res - M * DD; // placeholder, set below
    yb = (float*)(po) + 0; // NOT used; real assignment below

    dim3 blk(256);
    // qkv = x @ W_in^T  [M,512]
    gemm_kernel<<<dim3(M / 32, 8), blk, 0, stream>>>(x, 128, W_in, qkv, 512, 0);
    // residual = x @ W_res^T [M,128]
    gemm_kernel<<<dim3(M / 32, 2), blk, 0, stream>>>(x, 128, W_res, res, 128, 0);
    // alpha/beta = sigmoid(gate @ W_gate^T) [M,256]
    gemm_kernel<<<dim3(M / 32, 4), blk, 0, stream>>>(qkv + 384, 512, W_gate, abv, 256, 1);
    // q/k conv + sigmoid + l2norm -> qn, kam=[k|beta*k]
    convnorm_kernel<<<dim3(M / 4), blk, 0, stream>>>(qkv, qcw, qcb, kcw, kcb, abv,
                                                     qnb, kam);
    // recurrence (barrier-free, one wave per WG, depth-2 pipeline)
    recur_kernel<<<dim3(BB * GG), dim3(64), 0, stream>>>(qnb, kam, abv, qkv,
                                                         state, po, sfin);
    // combine partials + silu  (oc overwrites qnb — recurrence done with it)
    combine_silu_kernel<<<dim3((M * DD) / 1024), blk, 0, stream>>>((const ushort*)po, oc);
    // y = out_core @ W_out^T   (write into kam region — no longer needed)
    yb = kam;
    gemm_kernel<<<dim3(M / 32, 2), blk, 0, stream>>>(oc, 128, W_out, yb, 128, 0);
    // RMS + residual -> d_out
    rms_res_kernel<<<dim3(M / 4), blk, 0, stream>>>(yb, res, rmsw, out);
}

// Round 5
// 1059.945 us; speedup vs baseline: 1.4436x; 1.4436x over previous
//
#include <hip/hip_runtime.h>
#include <hip/hip_bf16.h>
#include <math.h>

#define BB 8
#define LL 2048
#define DD 128
#define GG 16   // state-row groups (8 rows per group, one wave each)

// ---------------------------------------------------------------------------
// DPP helpers: full-rate VALU cross-lane adds (NO LDS latency).
// 8-lane allreduce = quad_perm(xor1) + quad_perm(xor2) + row_half_mirror.
// ctrl must be a compile-time constant -> template parameter.
// ---------------------------------------------------------------------------
template <int CTRL>
__device__ __forceinline__ float dpp_add(float x) {
    int xi = __float_as_int(x);
    int yi = __builtin_amdgcn_update_dpp(xi, xi, CTRL, 0xF, 0xF, false);
    return x + __int_as_float(yi);
}
#define DPP_XOR1  0xB1   // quad_perm [1,0,3,2]
#define DPP_XOR2  0x4E   // quad_perm [2,3,0,1]
#define DPP_HMIRR 0x141  // row_half_mirror

// ---------------------------------------------------------------------------
// Generic C[M,O] = X[M,128] @ W[O,128]^T, optional sigmoid epilogue.
// ---------------------------------------------------------------------------
__global__ __launch_bounds__(256) void gemm_kernel(
    const float* __restrict__ X, int ldx,
    const float* __restrict__ W,
    float* __restrict__ C, int ldc,
    int applySig)
{
    __shared__ float Xs[32 * 132];
    __shared__ float Ws[64 * 132];
    const int tid = threadIdx.x;
    const int m0 = blockIdx.x * 32;
    const int o0 = blockIdx.y * 64;
    {
        int row = tid >> 3, cg = tid & 7;
        const float* src = X + (size_t)(m0 + row) * ldx + cg * 16;
        float* dst = Xs + row * 132 + cg * 16;
#pragma unroll
        for (int u = 0; u < 4; ++u)
            *(float4*)(dst + 4 * u) = *(const float4*)(src + 4 * u);
    }
    {
        int o = tid >> 2, cg = tid & 3;
        const float* src = W + (size_t)(o0 + o) * 128 + cg * 32;
        float* dst = Ws + o * 132 + cg * 32;
#pragma unroll
        for (int u = 0; u < 8; ++u)
            *(float4*)(dst + 4 * u) = *(const float4*)(src + 4 * u);
    }
    __syncthreads();
    const int tx = tid & 31, ty = tid >> 5;
    float acc[4][2] = {};
    const float* xb = Xs + (ty * 4) * 132;
    const float* wb = Ws + (tx * 2) * 132;
    for (int k0 = 0; k0 < 128; k0 += 4) {
        float4 xr[4], wr[2];
#pragma unroll
        for (int r = 0; r < 4; ++r) xr[r] = *(const float4*)(xb + r * 132 + k0);
#pragma unroll
        for (int cc = 0; cc < 2; ++cc) wr[cc] = *(const float4*)(wb + cc * 132 + k0);
#pragma unroll
        for (int r = 0; r < 4; ++r)
#pragma unroll
            for (int cc = 0; cc < 2; ++cc) {
                acc[r][cc] += xr[r].x * wr[cc].x + xr[r].y * wr[cc].y
                            + xr[r].z * wr[cc].z + xr[r].w * wr[cc].w;
            }
    }
#pragma unroll
    for (int r = 0; r < 4; ++r)
#pragma unroll
        for (int cc = 0; cc < 2; ++cc) {
            float v = acc[r][cc];
            if (applySig) v = 1.0f / (1.0f + __expf(-v));
            C[(size_t)(m0 + ty * 4 + r) * ldc + o0 + tx * 2 + cc] = v;
        }
}

// ---------------------------------------------------------------------------
// Depthwise conv(K=3, pad 1) + sigmoid + L2-normalize over D for q and k.
// Emits qn [M,128] and kam [M,256] = [ k_norm | m=beta*k_norm ].
// ---------------------------------------------------------------------------
__global__ __launch_bounds__(256) void convnorm_kernel(
    const float* __restrict__ qkv,
    const float* __restrict__ qw, const float* __restrict__ qb,
    const float* __restrict__ kw, const float* __restrict__ kb,
    const float* __restrict__ ab,
    float* __restrict__ qn, float* __restrict__ kam)
{
    const int tid = threadIdx.x;
    const int lane = tid & 63;
    const int wid = tid >> 6;
    const int m = blockIdx.x * 4 + wid;     // b*L + l
    const int l = m & (LL - 1);
    const int d0 = lane * 2;
    float yq0 = qb[d0], yq1 = qb[d0 + 1];
    float yk0 = kb[d0], yk1 = kb[d0 + 1];
#pragma unroll
    for (int tau = 0; tau < 3; ++tau) {
        int lp = l + tau - 1;
        if (lp >= 0 && lp < LL) {
            const float* base = qkv + (size_t)(m + tau - 1) * 512;
            yq0 += base[d0]       * qw[d0 * 3 + tau];
            yq1 += base[d0 + 1]   * qw[(d0 + 1) * 3 + tau];
            yk0 += base[128 + d0]     * kw[d0 * 3 + tau];
            yk1 += base[128 + d0 + 1] * kw[(d0 + 1) * 3 + tau];
        }
    }
    yq0 = 1.0f / (1.0f + __expf(-yq0));
    yq1 = 1.0f / (1.0f + __expf(-yq1));
    yk0 = 1.0f / (1.0f + __expf(-yk0));
    yk1 = 1.0f / (1.0f + __expf(-yk1));
    float sq = yq0 * yq0 + yq1 * yq1;
    float sk = yk0 * yk0 + yk1 * yk1;
#pragma unroll
    for (int msk = 1; msk <= 32; msk <<= 1) {
        sq += __shfl_xor(sq, msk);
        sk += __shfl_xor(sk, msk);
    }
    float rq = 1.0f / fmaxf(sqrtf(sq), 1e-12f);
    float rk = 1.0f / fmaxf(sqrtf(sk), 1e-12f);
    float k0n = yk0 * rk, k1n = yk1 * rk;
    size_t oq = (size_t)m * DD + d0;
    qn[oq] = yq0 * rq; qn[oq + 1] = yq1 * rq;
    float b0 = ab[(size_t)m * 256 + 128 + d0];
    float b1 = ab[(size_t)m * 256 + 128 + d0 + 1];
    size_t ok = (size_t)m * 256 + d0;
    kam[ok] = k0n;            kam[ok + 1] = k1n;
    kam[ok + 128] = b0 * k0n; kam[ok + 129] = b1 * k1n;
}

// ---------------------------------------------------------------------------
// Barrier-free sequential delta-rule recurrence, depth-2 pipeline, and —
// critically — NO LDS-based cross-lane ops in the serial chain:
//   * 8-lane Sk allreduce via DPP adds (VALU-rate)
//   * sk[0..7] broadcast via v_readlane -> SGPRs
// (R3 lesson: ds_swizzle/ds_bpermute = ~120cyc serial LDS latency each, at
//  1 wave/SIMD nothing hides it; that was the dominant per-step term.)
// ---------------------------------------------------------------------------
__global__ __launch_bounds__(64) void recur_kernel(
    const float* __restrict__ qn, const float* __restrict__ kam,
    const float* __restrict__ ab, const float* __restrict__ qkv,
    const float* __restrict__ state,
    __hip_bfloat16* __restrict__ pout, float* __restrict__ sfin)
{
    const int lane = threadIdx.x;
    const int b = blockIdx.x >> 4;
    const int g = blockIdx.x & (GG - 1);
    const int rbase = g * 8;
    const int iA = lane >> 3;
    const int c = lane & 7;
    const int colA = c * 16;
    const size_t mb = (size_t)b * LL;

    float SA[16];
    {
        const float* sp = state + ((size_t)b * DD + rbase + iA) * DD + colA;
#pragma unroll
        for (int u = 0; u < 4; ++u) {
            float4 t4 = *(const float4*)(sp + 4 * u);
            SA[4 * u + 0] = t4.x; SA[4 * u + 1] = t4.y;
            SA[4 * u + 2] = t4.z; SA[4 * u + 3] = t4.w;
        }
    }
    float SB[8][2];
#pragma unroll
    for (int r = 0; r < 8; ++r) {
        const float* sp = state + ((size_t)b * DD + rbase + r) * DD + lane;
        SB[r][0] = sp[0]; SB[r][1] = sp[64];
    }

    // streaming pointers (advance once per PREFETCH)
    const float* pA  = kam + mb * 256 + colA;   // k at +0, m at +128 floats
    const float* pAa = ab  + mb * 256 + colA;   // alpha (first half of ab)
    const float* pBk = kam + mb * 256 + lane;   // mB0 at +128, mB1 at +192
    const float* pBa = ab  + mb * 256 + lane;   // aB0 at +0,  aB1 at +64
    const float* pV  = qkv + mb * 512 + 256 + rbase;
    const float* pQ  = qn  + mb * DD + rbase;
    __hip_bfloat16* po = pout + ((size_t)g * (BB * LL) + mb) * DD + lane;

    // double-buffered per-step registers (statically indexed)
    float ka[2][16], aa[2][16], ma[2][16];
    float vv[2][8], qv[2][8];
    float vA[2], aB0[2], aB1[2], mB0[2], mB1[2];

#define PREFETCH(B)                                                          \
    do {                                                                     \
        _Pragma("unroll")                                                    \
        for (int u = 0; u < 4; ++u) {                                        \
            float4 t4;                                                       \
            t4 = *(const float4*)(pA + 4 * u);                               \
            ka[B][4*u] = t4.x; ka[B][4*u+1] = t4.y;                          \
            ka[B][4*u+2] = t4.z; ka[B][4*u+3] = t4.w;                        \
            t4 = *(const float4*)(pA + 128 + 4 * u);                         \
            ma[B][4*u] = t4.x; ma[B][4*u+1] = t4.y;                          \
            ma[B][4*u+2] = t4.z; ma[B][4*u+3] = t4.w;                        \
            t4 = *(const float4*)(pAa + 4 * u);                              \
            aa[B][4*u] = t4.x; aa[B][4*u+1] = t4.y;                          \
            aa[B][4*u+2] = t4.z; aa[B][4*u+3] = t4.w;                        \
        }                                                                    \
        {                                                                    \
            float4 t4;                                                       \
            t4 = *(const float4*)pV;                                         \
            vv[B][0] = t4.x; vv[B][1] = t4.y; vv[B][2] = t4.z; vv[B][3] = t4.w; \
            t4 = *(const float4*)(pV + 4);                                   \
            vv[B][4] = t4.x; vv[B][5] = t4.y; vv[B][6] = t4.z; vv[B][7] = t4.w; \
            t4 = *(const float4*)pQ;                                         \
            qv[B][0] = t4.x; qv[B][1] = t4.y; qv[B][2] = t4.z; qv[B][3] = t4.w; \
            t4 = *(const float4*)(pQ + 4);                                   \
            qv[B][4] = t4.x; qv[B][5] = t4.y; qv[B][6] = t4.z; qv[B][7] = t4.w; \
        }                                                                    \
        vA[B] = pV[iA];                                                      \
        aB0[B] = pBa[0];   aB1[B] = pBa[64];                                 \
        mB0[B] = pBk[128]; mB1[B] = pBk[192];                                \
        pA += 256; pAa += 256; pBk += 256; pBa += 256; pV += 512; pQ += DD;  \
    } while (0)

#define STEP(B)                                                              \
    do {                                                                     \
        /* Sk dot: 4 independent FMA chains + tree join (dep depth ~6) */    \
        float c0 = SA[0] * ka[B][0], c1 = SA[1] * ka[B][1];                  \
        float c2 = SA[2] * ka[B][2], c3 = SA[3] * ka[B][3];                  \
        _Pragma("unroll")                                                    \
        for (int u = 1; u < 4; ++u) {                                        \
            c0 = fmaf(SA[4*u+0], ka[B][4*u+0], c0);                          \
            c1 = fmaf(SA[4*u+1], ka[B][4*u+1], c1);                          \
            c2 = fmaf(SA[4*u+2], ka[B][4*u+2], c2);                          \
            c3 = fmaf(SA[4*u+3], ka[B][4*u+3], c3);                          \
        }                                                                    \
        float p = (c0 + c1) + (c2 + c3);                                     \
        /* 8-lane allreduce, pure VALU DPP */                                \
        p = dpp_add<DPP_XOR1>(p);                                            \
        p = dpp_add<DPP_XOR2>(p);                                            \
        p = dpp_add<DPP_HMIRR>(p);                                           \
        /* broadcast all 8 rows' Sk via readlane -> SGPRs */                 \
        float sk[8];                                                         \
        _Pragma("unroll")                                                    \
        for (int r = 0; r < 8; ++r)                                          \
            sk[r] = __int_as_float(                                          \
                __builtin_amdgcn_readlane(__float_as_int(p), r * 8));        \
        _Pragma("unroll")                                                    \
        for (int u = 0; u < 16; ++u) {                                       \
            float w = fmaf(-aa[B][u], p, vA[B]);                             \
            SA[u] = fmaf(ma[B][u], w, aa[B][u] * SA[u]);                     \
        }                                                                    \
        float po0 = 0.0f, po1 = 0.0f;                                        \
        _Pragma("unroll")                                                    \
        for (int r = 0; r < 8; ++r) {                                        \
            float w0 = fmaf(-aB0[B], sk[r], vv[B][r]);                       \
            SB[r][0] = fmaf(mB0[B], w0, aB0[B] * SB[r][0]);                  \
            po0 = fmaf(qv[B][r], SB[r][0], po0);                             \
            float w1 = fmaf(-aB1[B], sk[r], vv[B][r]);                       \
            SB[r][1] = fmaf(mB1[B], w1, aB1[B] * SB[r][1]);                  \
            po1 = fmaf(qv[B][r], SB[r][1], po1);                             \
        }                                                                    \
        po[0]  = __float2bfloat16(po0);                                      \
        po[64] = __float2bfloat16(po1);                                      \
        po += DD;                                                            \
    } while (0)

    PREFETCH(0);    // t = 0
    PREFETCH(1);    // t = 1
    for (int t = 0; t < LL; t += 2) {
        STEP(0);
        PREFETCH(0);    // t+2 (tail overruns into adjacent ws buffers: safe)
        STEP(1);
        PREFETCH(1);    // t+3
    }
#undef PREFETCH
#undef STEP

    {
        float* sp = sfin + ((size_t)b * DD + rbase + iA) * DD + colA;
#pragma unroll
        for (int u = 0; u < 4; ++u) {
            float4 o4 = {SA[4*u], SA[4*u+1], SA[4*u+2], SA[4*u+3]};
            *(float4*)(sp + 4 * u) = o4;
        }
    }
}

// ---------------------------------------------------------------------------
// out_core = silu(sum_g pout[g])   (pout bf16 -> fp32 accumulate)
// ---------------------------------------------------------------------------
__global__ __launch_bounds__(256) void combine_silu_kernel(
    const ushort* __restrict__ pout, float* __restrict__ oc)
{
    const size_t N = (size_t)BB * LL * DD;
    size_t idx = ((size_t)blockIdx.x * 256 + threadIdx.x) * 4;
    float s0 = 0, s1 = 0, s2 = 0, s3 = 0;
#pragma unroll
    for (int g = 0; g < GG; ++g) {
        uint2 u = *(const uint2*)(pout + g * N + idx);
        s0 += __uint_as_float((u.x & 0xffffu) << 16);
        s1 += __uint_as_float(u.x & 0xffff0000u);
        s2 += __uint_as_float((u.y & 0xffffu) << 16);
        s3 += __uint_as_float(u.y & 0xffff0000u);
    }
    float4 r;
    r.x = s0 / (1.0f + __expf(-s0));
    r.y = s1 / (1.0f + __expf(-s1));
    r.z = s2 / (1.0f + __expf(-s2));
    r.w = s3 / (1.0f + __expf(-s3));
    *(float4*)(oc + idx) = r;
}

// ---------------------------------------------------------------------------
// d_out = y * rsqrt(mean(y^2)+1e-6) * rms_w + residual. One wave per (b,l).
// ---------------------------------------------------------------------------
__global__ __launch_bounds__(256) void rms_res_kernel(
    const float* __restrict__ y, const float* __restrict__ res,
    const float* __restrict__ rmsw, float* __restrict__ out)
{
    const int tid = threadIdx.x;
    const int lane = tid & 63;
    const int wid = tid >> 6;
    const int m = blockIdx.x * 4 + wid;
    const int d0 = lane * 2;
    size_t o = (size_t)m * DD + d0;
    float2 yv = *(const float2*)(y + o);
    float ss = yv.x * yv.x + yv.y * yv.y;
#pragma unroll
    for (int msk = 1; msk <= 32; msk <<= 1) ss += __shfl_xor(ss, msk);
    float r = rsqrtf(ss * (1.0f / 128.0f) + 1e-6f);
    float2 rv = *(const float2*)(res + o);
    out[o]     = yv.x * r * rmsw[d0]     + rv.x;
    out[o + 1] = yv.y * r * rmsw[d0 + 1] + rv.y;
}

// ---------------------------------------------------------------------------
extern "C" void kernel_launch(void* const* d_in, const int* in_sizes, int n_in,
                              void* d_out, int out_size, void* d_ws, size_t ws_size,
                              hipStream_t stream)
{
    const float* x      = (const float*)d_in[0];
    const float* state  = (const float*)d_in[1];
    const float* W_in   = (const float*)d_in[2];
    const float* W_gate = (const float*)d_in[3];
    const float* W_out  = (const float*)d_in[4];
    const float* W_res  = (const float*)d_in[5];
    const float* qcw    = (const float*)d_in[6];
    const float* qcb    = (const float*)d_in[7];
    const float* kcw    = (const float*)d_in[8];
    const float* kcb    = (const float*)d_in[9];
    const float* rmsw   = (const float*)d_in[10];
    float* out  = (float*)d_out;
    float* sfin = out + (size_t)BB * LL * DD;

    const size_t M = (size_t)BB * LL;            // 16384
    float* ws = (float*)d_ws;
    float* qkv = ws;                 ws += M * 512;           // 33.5 MB
    float* abv = ws;                 ws += M * 256;           // 16.8 MB
    float* res = ws;                 ws += M * DD;            //  8.4 MB
    float* qnb = ws;                 ws += M * DD;            //  8.4 MB
    float* kam = ws;                 ws += M * 256;           // 16.8 MB
    __hip_bfloat16* po = (__hip_bfloat16*)ws;                 // 67 MB (GG slices)
    float* oc = qnb;   // combine output: recurrence no longer reads qnb after
    float* yb = kam;   // W_out GEMM output: kam no longer needed after recur

    dim3 blk(256);
    // qkv = x @ W_in^T  [M,512]
    gemm_kernel<<<dim3(M / 32, 8), blk, 0, stream>>>(x, 128, W_in, qkv, 512, 0);
    // residual = x @ W_res^T [M,128]
    gemm_kernel<<<dim3(M / 32, 2), blk, 0, stream>>>(x, 128, W_res, res, 128, 0);
    // alpha/beta = sigmoid(gate @ W_gate^T) [M,256]
    gemm_kernel<<<dim3(M / 32, 4), blk, 0, stream>>>(qkv + 384, 512, W_gate, abv, 256, 1);
    // q/k conv + sigmoid + l2norm -> qn, kam=[k|beta*k]
    convnorm_kernel<<<dim3(M / 4), blk, 0, stream>>>(qkv, qcw, qcb, kcw, kcb, abv,
                                                     qnb, kam);
    // recurrence (barrier-free, one wave per WG, depth-2 pipeline, DPP reduce)
    recur_kernel<<<dim3(BB * GG), dim3(64), 0, stream>>>(qnb, kam, abv, qkv,
                                                         state, po, sfin);
    // combine partials + silu  (oc overwrites qnb — recurrence done with it)
    combine_silu_kernel<<<dim3((M * DD) / 1024), blk, 0, stream>>>((const ushort*)po, oc);
    // y = out_core @ W_out^T
    gemm_kernel<<<dim3(M / 32, 2), blk, 0, stream>>>(oc, 128, W_out, yb, 128, 0);
    // RMS + residual -> d_out
    rms_res_kernel<<<dim3(M / 4), blk, 0, stream>>>(yb, res, rmsw, out);
}

// Round 7
// 937.417 us; speedup vs baseline: 1.6323x; 1.1307x over previous
//
#include <hip/hip_runtime.h>
#include <hip/hip_bf16.h>
#include <math.h>

#define BB 8
#define LL 2048
#define DD 128

// ---------------------------------------------------------------------------
// DPP helpers: full-rate VALU cross-lane adds (NO LDS latency).
// ctrl must be a compile-time constant -> template parameter.
// ---------------------------------------------------------------------------
template <int CTRL>
__device__ __forceinline__ float dpp_add(float x) {
    int xi = __float_as_int(x);
    int yi = __builtin_amdgcn_update_dpp(xi, xi, CTRL, 0xF, 0xF, false);
    return x + __int_as_float(yi);
}
// LPR-lane allreduce (LPR = lanes per state row, rows aligned to LPR):
template <int LPR>
__device__ __forceinline__ float allreduce_lpr(float p) {
    p = dpp_add<0xB1>(p);                       // quad_perm [1,0,3,2]  (^1)
    p = dpp_add<0x4E>(p);                       // quad_perm [2,3,0,1]  (^2)
    if constexpr (LPR >= 8)  p = dpp_add<0x141>(p);   // row_half_mirror (^:8)
    if constexpr (LPR >= 16) p = dpp_add<0x140>(p);   // row_mirror (^:16)
    return p;
}

// ---------------------------------------------------------------------------
// Generic C[M,O] = X[M,128] @ W[O,128]^T, optional sigmoid epilogue.
// ---------------------------------------------------------------------------
__global__ __launch_bounds__(256) void gemm_kernel(
    const float* __restrict__ X, int ldx,
    const float* __restrict__ W,
    float* __restrict__ C, int ldc,
    int applySig)
{
    __shared__ float Xs[32 * 132];
    __shared__ float Ws[64 * 132];
    const int tid = threadIdx.x;
    const int m0 = blockIdx.x * 32;
    const int o0 = blockIdx.y * 64;
    {
        int row = tid >> 3, cg = tid & 7;
        const float* src = X + (size_t)(m0 + row) * ldx + cg * 16;
        float* dst = Xs + row * 132 + cg * 16;
#pragma unroll
        for (int u = 0; u < 4; ++u)
            *(float4*)(dst + 4 * u) = *(const float4*)(src + 4 * u);
    }
    {
        int o = tid >> 2, cg = tid & 3;
        const float* src = W + (size_t)(o0 + o) * 128 + cg * 32;
        float* dst = Ws + o * 132 + cg * 32;
#pragma unroll
        for (int u = 0; u < 8; ++u)
            *(float4*)(dst + 4 * u) = *(const float4*)(src + 4 * u);
    }
    __syncthreads();
    const int tx = tid & 31, ty = tid >> 5;
    float acc[4][2] = {};
    const float* xb = Xs + (ty * 4) * 132;
    const float* wb = Ws + (tx * 2) * 132;
    for (int k0 = 0; k0 < 128; k0 += 4) {
        float4 xr[4], wr[2];
#pragma unroll
        for (int r = 0; r < 4; ++r) xr[r] = *(const float4*)(xb + r * 132 + k0);
#pragma unroll
        for (int cc = 0; cc < 2; ++cc) wr[cc] = *(const float4*)(wb + cc * 132 + k0);
#pragma unroll
        for (int r = 0; r < 4; ++r)
#pragma unroll
            for (int cc = 0; cc < 2; ++cc) {
                acc[r][cc] += xr[r].x * wr[cc].x + xr[r].y * wr[cc].y
                            + xr[r].z * wr[cc].z + xr[r].w * wr[cc].w;
            }
    }
#pragma unroll
    for (int r = 0; r < 4; ++r)
#pragma unroll
        for (int cc = 0; cc < 2; ++cc) {
            float v = acc[r][cc];
            if (applySig) v = 1.0f / (1.0f + __expf(-v));
            C[(size_t)(m0 + ty * 4 + r) * ldc + o0 + tx * 2 + cc] = v;
        }
}

// ---------------------------------------------------------------------------
// Depthwise conv(K=3) + sigmoid + L2-norm for q,k; packs the recurrence
// stream:  pack[M,640] = [ k(128) | m=beta*k(128) | alpha(128) | q(128) | v(128) ]
// ---------------------------------------------------------------------------
__global__ __launch_bounds__(256) void convnorm_kernel(
    const float* __restrict__ qkv,
    const float* __restrict__ qw, const float* __restrict__ qb,
    const float* __restrict__ kw, const float* __restrict__ kb,
    const float* __restrict__ ab,
    float* __restrict__ pack)
{
    const int tid = threadIdx.x;
    const int lane = tid & 63;
    const int wid = tid >> 6;
    const int m = blockIdx.x * 4 + wid;     // b*L + l
    const int l = m & (LL - 1);
    const int d0 = lane * 2;
    float yq0 = qb[d0], yq1 = qb[d0 + 1];
    float yk0 = kb[d0], yk1 = kb[d0 + 1];
#pragma unroll
    for (int tau = 0; tau < 3; ++tau) {
        int lp = l + tau - 1;
        if (lp >= 0 && lp < LL) {
            const float* base = qkv + (size_t)(m + tau - 1) * 512;
            yq0 += base[d0]       * qw[d0 * 3 + tau];
            yq1 += base[d0 + 1]   * qw[(d0 + 1) * 3 + tau];
            yk0 += base[128 + d0]     * kw[d0 * 3 + tau];
            yk1 += base[128 + d0 + 1] * kw[(d0 + 1) * 3 + tau];
        }
    }
    yq0 = 1.0f / (1.0f + __expf(-yq0));
    yq1 = 1.0f / (1.0f + __expf(-yq1));
    yk0 = 1.0f / (1.0f + __expf(-yk0));
    yk1 = 1.0f / (1.0f + __expf(-yk1));
    float sq = yq0 * yq0 + yq1 * yq1;
    float sk = yk0 * yk0 + yk1 * yk1;
#pragma unroll
    for (int msk = 1; msk <= 32; msk <<= 1) {
        sq += __shfl_xor(sq, msk);
        sk += __shfl_xor(sk, msk);
    }
    float rq = 1.0f / fmaxf(sqrtf(sq), 1e-12f);
    float rk = 1.0f / fmaxf(sqrtf(sk), 1e-12f);
    float k0n = yk0 * rk, k1n = yk1 * rk;
    float a0 = ab[(size_t)m * 256 + d0];
    float a1 = ab[(size_t)m * 256 + d0 + 1];
    float b0 = ab[(size_t)m * 256 + 128 + d0];
    float b1 = ab[(size_t)m * 256 + 128 + d0 + 1];
    float v0 = qkv[(size_t)m * 512 + 256 + d0];
    float v1 = qkv[(size_t)m * 512 + 256 + d0 + 1];
    float* P = pack + (size_t)m * 640;
    P[d0]       = k0n;      P[d0 + 1]       = k1n;
    P[128 + d0] = b0 * k0n; P[128 + d0 + 1] = b1 * k1n;
    P[256 + d0] = a0;       P[256 + d0 + 1] = a1;
    P[384 + d0] = yq0 * rq; P[384 + d0 + 1] = yq1 * rq;
    P[512 + d0] = v0;       P[512 + d0 + 1] = v1;
}

// ---------------------------------------------------------------------------
// Barrier-free sequential delta-rule recurrence. Template R = state rows per
// wave. Grid = BB * (DD/R) workgroups of 64 threads (one wave each).
// Two register layouts of the same state slice:
//   A: lane (iA=lane/LPR, c=lane%LPR) holds S[rbase+iA][c*CW .. +CW)
//   B: lane holds cols {lane, lane+64} of the R rows  (q^T S local)
// Partial-output layout MUST be slice-major to match combine_silu:
//   pout[g*(BB*LL*DD) + (b*LL + t)*DD + d]      (R6 bug: was batch-major)
// ---------------------------------------------------------------------------
template <int R>
__global__ __launch_bounds__(64) void recur_kernel(
    const float* __restrict__ pack, const float* __restrict__ state,
    __hip_bfloat16* __restrict__ pout, float* __restrict__ sfin)
{
    constexpr int LPR = 64 / R;       // lanes per row (A layout)
    constexpr int CW  = DD / LPR;     // cols per lane (A layout)
    constexpr int NG  = DD / R;       // groups per batch
    const int lane = threadIdx.x;
    const int b = blockIdx.x / NG;
    const int g = blockIdx.x % NG;
    const int rbase = g * R;
    const int iA = lane / LPR;
    const int c  = lane % LPR;
    const int colA = c * CW;
    const size_t mb = (size_t)b * LL;

    float SA[CW];
    {
        const float* sp = state + ((size_t)b * DD + rbase + iA) * DD + colA;
#pragma unroll
        for (int u = 0; u < CW / 4; ++u) {
            float4 t4 = *(const float4*)(sp + 4 * u);
            SA[4*u] = t4.x; SA[4*u+1] = t4.y; SA[4*u+2] = t4.z; SA[4*u+3] = t4.w;
        }
    }
    float SB[R][2];
#pragma unroll
    for (int r = 0; r < R; ++r) {
        const float* sp = state + ((size_t)b * DD + rbase + r) * DD + lane;
        SB[r][0] = sp[0]; SB[r][1] = sp[64];
    }

    const float* P = pack + mb * 640;
    __hip_bfloat16* po = pout + ((size_t)g * (BB * LL) + mb) * DD + lane;

    // double-buffered per-step registers (statically indexed)
    float ka[2][CW], ma[2][CW], aa[2][CW];
    float vv[2][R], qv[2][R];
    float vA[2], aB0[2], aB1[2], mB0[2], mB1[2];

#define PREFETCH(Bf)                                                         \
    do {                                                                     \
        _Pragma("unroll")                                                    \
        for (int u = 0; u < CW / 4; ++u) {                                   \
            float4 t4;                                                       \
            t4 = *(const float4*)(P + colA + 4 * u);                         \
            ka[Bf][4*u] = t4.x; ka[Bf][4*u+1] = t4.y;                        \
            ka[Bf][4*u+2] = t4.z; ka[Bf][4*u+3] = t4.w;                      \
            t4 = *(const float4*)(P + 128 + colA + 4 * u);                   \
            ma[Bf][4*u] = t4.x; ma[Bf][4*u+1] = t4.y;                        \
            ma[Bf][4*u+2] = t4.z; ma[Bf][4*u+3] = t4.w;                      \
            t4 = *(const float4*)(P + 256 + colA + 4 * u);                   \
            aa[Bf][4*u] = t4.x; aa[Bf][4*u+1] = t4.y;                        \
            aa[Bf][4*u+2] = t4.z; aa[Bf][4*u+3] = t4.w;                      \
        }                                                                    \
        _Pragma("unroll")                                                    \
        for (int u = 0; u < R / 4; ++u) {                                    \
            float4 t4;                                                       \
            t4 = *(const float4*)(P + 384 + rbase + 4 * u);                  \
            qv[Bf][4*u] = t4.x; qv[Bf][4*u+1] = t4.y;                        \
            qv[Bf][4*u+2] = t4.z; qv[Bf][4*u+3] = t4.w;                      \
            t4 = *(const float4*)(P + 512 + rbase + 4 * u);                  \
            vv[Bf][4*u] = t4.x; vv[Bf][4*u+1] = t4.y;                        \
            vv[Bf][4*u+2] = t4.z; vv[Bf][4*u+3] = t4.w;                      \
        }                                                                    \
        vA[Bf]  = P[512 + rbase + iA];                                       \
        aB0[Bf] = P[256 + lane]; aB1[Bf] = P[256 + lane + 64];               \
        mB0[Bf] = P[128 + lane]; mB1[Bf] = P[128 + lane + 64];               \
        P += 640;                                                            \
    } while (0)

#define STEP(Bf)                                                             \
    do {                                                                     \
        /* Sk dot: independent chains + tree join */                         \
        float c0 = SA[0] * ka[Bf][0], c1 = SA[1] * ka[Bf][1];                \
        float c2 = SA[2] * ka[Bf][2], c3 = SA[3] * ka[Bf][3];                \
        _Pragma("unroll")                                                    \
        for (int u = 1; u < CW / 4; ++u) {                                   \
            c0 = fmaf(SA[4*u+0], ka[Bf][4*u+0], c0);                         \
            c1 = fmaf(SA[4*u+1], ka[Bf][4*u+1], c1);                         \
            c2 = fmaf(SA[4*u+2], ka[Bf][4*u+2], c2);                         \
            c3 = fmaf(SA[4*u+3], ka[Bf][4*u+3], c3);                         \
        }                                                                    \
        float p = (c0 + c1) + (c2 + c3);                                     \
        p = allreduce_lpr<LPR>(p);                                           \
        float sk[R];                                                         \
        _Pragma("unroll")                                                    \
        for (int r = 0; r < R; ++r)                                          \
            sk[r] = __int_as_float(                                          \
                __builtin_amdgcn_readlane(__float_as_int(p), r * LPR));      \
        _Pragma("unroll")                                                    \
        for (int u = 0; u < CW; ++u) {                                       \
            float w = fmaf(-aa[Bf][u], p, vA[Bf]);                           \
            SA[u] = fmaf(ma[Bf][u], w, aa[Bf][u] * SA[u]);                   \
        }                                                                    \
        float po0 = 0.0f, po1 = 0.0f;                                        \
        _Pragma("unroll")                                                    \
        for (int r = 0; r < R; ++r) {                                        \
            float w0 = fmaf(-aB0[Bf], sk[r], vv[Bf][r]);                     \
            SB[r][0] = fmaf(mB0[Bf], w0, aB0[Bf] * SB[r][0]);                \
            po0 = fmaf(qv[Bf][r], SB[r][0], po0);                            \
            float w1 = fmaf(-aB1[Bf], sk[r], vv[Bf][r]);                     \
            SB[r][1] = fmaf(mB1[Bf], w1, aB1[Bf] * SB[r][1]);                \
            po1 = fmaf(qv[Bf][r], SB[r][1], po1);                            \
        }                                                                    \
        po[0]  = __float2bfloat16(po0);                                      \
        po[64] = __float2bfloat16(po1);                                      \
        po += DD;                                                            \
    } while (0)

    PREFETCH(0);    // t = 0
    PREFETCH(1);    // t = 1
    for (int t = 0; t < LL; t += 2) {
        STEP(0);
        PREFETCH(0);    // t+2 (tail overruns into ws: values unused)
        STEP(1);
        PREFETCH(1);    // t+3
    }
#undef PREFETCH
#undef STEP

    {
        float* sp = sfin + ((size_t)b * DD + rbase + iA) * DD + colA;
#pragma unroll
        for (int u = 0; u < CW / 4; ++u) {
            float4 o4 = {SA[4*u], SA[4*u+1], SA[4*u+2], SA[4*u+3]};
            *(float4*)(sp + 4 * u) = o4;
        }
    }
}

// ---------------------------------------------------------------------------
// out_core = silu(sum_s pout[s])   (pout bf16 -> fp32 accumulate)
// ---------------------------------------------------------------------------
__global__ __launch_bounds__(256) void combine_silu_kernel(
    const ushort* __restrict__ pout, float* __restrict__ oc, int nsl)
{
    const size_t N = (size_t)BB * LL * DD;
    size_t idx = ((size_t)blockIdx.x * 256 + threadIdx.x) * 4;
    float s0 = 0, s1 = 0, s2 = 0, s3 = 0;
    for (int g = 0; g < nsl; ++g) {
        uint2 u = *(const uint2*)(pout + g * N + idx);
        s0 += __uint_as_float((u.x & 0xffffu) << 16);
        s1 += __uint_as_float(u.x & 0xffff0000u);
        s2 += __uint_as_float((u.y & 0xffffu) << 16);
        s3 += __uint_as_float(u.y & 0xffff0000u);
    }
    float4 r;
    r.x = s0 / (1.0f + __expf(-s0));
    r.y = s1 / (1.0f + __expf(-s1));
    r.z = s2 / (1.0f + __expf(-s2));
    r.w = s3 / (1.0f + __expf(-s3));
    *(float4*)(oc + idx) = r;
}

// ---------------------------------------------------------------------------
// d_out = y * rsqrt(mean(y^2)+1e-6) * rms_w + residual. One wave per (b,l).
// ---------------------------------------------------------------------------
__global__ __launch_bounds__(256) void rms_res_kernel(
    const float* __restrict__ y, const float* __restrict__ res,
    const float* __restrict__ rmsw, float* __restrict__ out)
{
    const int tid = threadIdx.x;
    const int lane = tid & 63;
    const int wid = tid >> 6;
    const int m = blockIdx.x * 4 + wid;
    const int d0 = lane * 2;
    size_t o = (size_t)m * DD + d0;
    float2 yv = *(const float2*)(y + o);
    float ss = yv.x * yv.x + yv.y * yv.y;
#pragma unroll
    for (int msk = 1; msk <= 32; msk <<= 1) ss += __shfl_xor(ss, msk);
    float r = rsqrtf(ss * (1.0f / 128.0f) + 1e-6f);
    float2 rv = *(const float2*)(res + o);
    out[o]     = yv.x * r * rmsw[d0]     + rv.x;
    out[o + 1] = yv.y * r * rmsw[d0 + 1] + rv.y;
}

// ---------------------------------------------------------------------------
// Workspace overlays (byte offsets from d_ws):
//   [0, 41.9MB)      pack [M,640] fp32        (dead after recur; oc reuses)
//   [41.9MB, ...)    poreg:
//      phase 1 (GEMM/conv):  qkv [M,512] (33.5MB) + abv [M,256] (16.8MB)
//      phase 2 (recur):      pout bf16, nsl slices (67 MB R8 / 134 MB R4)
//      phase 3 (epilogue):   res [M,128] + yb [M,128]
// ---------------------------------------------------------------------------
extern "C" void kernel_launch(void* const* d_in, const int* in_sizes, int n_in,
                              void* d_out, int out_size, void* d_ws, size_t ws_size,
                              hipStream_t stream)
{
    const float* x      = (const float*)d_in[0];
    const float* state  = (const float*)d_in[1];
    const float* W_in   = (const float*)d_in[2];
    const float* W_gate = (const float*)d_in[3];
    const float* W_out  = (const float*)d_in[4];
    const float* W_res  = (const float*)d_in[5];
    const float* qcw    = (const float*)d_in[6];
    const float* qcb    = (const float*)d_in[7];
    const float* kcw    = (const float*)d_in[8];
    const float* kcb    = (const float*)d_in[9];
    const float* rmsw   = (const float*)d_in[10];
    float* out  = (float*)d_out;
    float* sfin = out + (size_t)BB * LL * DD;

    const size_t M = (size_t)BB * LL;            // 16384
    char* base = (char*)d_ws;
    const size_t PACK_BYTES = M * 640 * 4;       // 41.9 MB
    float* pack = (float*)base;
    char*  poreg = base + PACK_BYTES;
    float* qkv = (float*)poreg;                              // phase 1
    float* abv = (float*)(poreg + M * 512 * 4);              // phase 1
    __hip_bfloat16* po = (__hip_bfloat16*)poreg;             // phase 2
    float* oc  = pack;                                       // phase 3 (over pack)
    float* res = (float*)poreg;                              // phase 3 (over po)
    float* yb  = (float*)(poreg + M * DD * 4);               // phase 3

    // Pick recurrence split from available workspace (constant per session).
    const size_t need4 = PACK_BYTES + 32ull * M * DD * 2;    // 176.2 MB
    const bool useR4 = (ws_size >= need4);
    const int nsl = useR4 ? 32 : 16;

    dim3 blk(256);
    // qkv = x @ W_in^T  [M,512]
    gemm_kernel<<<dim3(M / 32, 8), blk, 0, stream>>>(x, 128, W_in, qkv, 512, 0);
    // alpha/beta = sigmoid(gate @ W_gate^T) [M,256]
    gemm_kernel<<<dim3(M / 32, 4), blk, 0, stream>>>(qkv + 384, 512, W_gate, abv, 256, 1);
    // conv + sigmoid + l2norm + pack stream [k|m|alpha|q|v]
    convnorm_kernel<<<dim3(M / 4), blk, 0, stream>>>(qkv, qcw, qcb, kcw, kcb, abv, pack);
    // recurrence (barrier-free, 1 wave/WG, depth-2 pipeline, DPP+readlane)
    if (useR4)
        recur_kernel<4><<<dim3(BB * 32), dim3(64), 0, stream>>>(pack, state, po, sfin);
    else
        recur_kernel<8><<<dim3(BB * 16), dim3(64), 0, stream>>>(pack, state, po, sfin);
    // combine partials + silu -> oc (overwrites pack; pack is dead)
    combine_silu_kernel<<<dim3((M * DD) / 1024), blk, 0, stream>>>(
        (const ushort*)po, oc, nsl);
    // residual = x @ W_res^T  (po region is dead after combine)
    gemm_kernel<<<dim3(M / 32, 2), blk, 0, stream>>>(x, 128, W_res, res, 128, 0);
    // y = oc @ W_out^T
    gemm_kernel<<<dim3(M / 32, 2), blk, 0, stream>>>(oc, 128, W_out, yb, 128, 0);
    // RMS + residual -> d_out
    rms_res_kernel<<<dim3(M / 4), blk, 0, stream>>>(yb, res, rmsw, out);
}